// Round 1
// baseline (27918.091 us; speedup 1.0000x reference)
//
#include <hip/hip_runtime.h>
#include <math.h>

#define HID 2048
#define SEQ 2048
#define N3  6144   // 3*HID
#define NBLK 256

// ---------------------------------------------------------------------------
// GEMM: GI = X @ W_ih^T + b_ih   (fp32, classic 128x128x16 LDS tile, 8x8/thread)
// X: [rows][HID] row-major, W: [N3][HID] row-major, GI: [rows][N3]
// ---------------------------------------------------------------------------
#define BM 128
#define BN 128
#define BK 16

__global__ __launch_bounds__(256)
void gi_gemm_kernel(const float* __restrict__ X, const float* __restrict__ W,
                    const float* __restrict__ bias, float* __restrict__ GI) {
  __shared__ float As[BK][BM + 4];
  __shared__ float Bs[BK][BN + 4];
  const int tid = threadIdx.x;
  const int bm = blockIdx.y * BM;
  const int bn = blockIdx.x * BN;
  const int tx = tid & 15;
  const int ty = tid >> 4;
  const int lr = tid >> 1;          // 0..127: row within tile
  const int lk = (tid & 1) * 8;     // 0 or 8: k-offset

  float acc[8][8];
#pragma unroll
  for (int i = 0; i < 8; ++i)
#pragma unroll
    for (int j = 0; j < 8; ++j) acc[i][j] = 0.f;

  const float* Arow = X + (size_t)(bm + lr) * HID + lk;
  const float* Brow = W + (size_t)(bn + lr) * HID + lk;

  for (int kc = 0; kc < HID; kc += BK) {
    float4 a0 = *(const float4*)(Arow + kc);
    float4 a1 = *(const float4*)(Arow + kc + 4);
    float4 b0 = *(const float4*)(Brow + kc);
    float4 b1 = *(const float4*)(Brow + kc + 4);
    __syncthreads();
    As[lk + 0][lr] = a0.x; As[lk + 1][lr] = a0.y; As[lk + 2][lr] = a0.z; As[lk + 3][lr] = a0.w;
    As[lk + 4][lr] = a1.x; As[lk + 5][lr] = a1.y; As[lk + 6][lr] = a1.z; As[lk + 7][lr] = a1.w;
    Bs[lk + 0][lr] = b0.x; Bs[lk + 1][lr] = b0.y; Bs[lk + 2][lr] = b0.z; Bs[lk + 3][lr] = b0.w;
    Bs[lk + 4][lr] = b1.x; Bs[lk + 5][lr] = b1.y; Bs[lk + 6][lr] = b1.z; Bs[lk + 7][lr] = b1.w;
    __syncthreads();
#pragma unroll
    for (int kk = 0; kk < BK; ++kk) {
      float4 av0 = *(const float4*)&As[kk][ty * 8];
      float4 av1 = *(const float4*)&As[kk][ty * 8 + 4];
      float4 bv0 = *(const float4*)&Bs[kk][tx * 8];
      float4 bv1 = *(const float4*)&Bs[kk][tx * 8 + 4];
      float a[8] = {av0.x, av0.y, av0.z, av0.w, av1.x, av1.y, av1.z, av1.w};
      float b[8] = {bv0.x, bv0.y, bv0.z, bv0.w, bv1.x, bv1.y, bv1.z, bv1.w};
#pragma unroll
      for (int i = 0; i < 8; ++i)
#pragma unroll
        for (int j = 0; j < 8; ++j)
          acc[i][j] = fmaf(a[i], b[j], acc[i][j]);
    }
  }

  const int n0 = bn + tx * 8;
  float bv[8];
#pragma unroll
  for (int j = 0; j < 8; ++j) bv[j] = bias[n0 + j];
#pragma unroll
  for (int i = 0; i < 8; ++i) {
    float4 o0, o1;
    o0.x = acc[i][0] + bv[0]; o0.y = acc[i][1] + bv[1];
    o0.z = acc[i][2] + bv[2]; o0.w = acc[i][3] + bv[3];
    o1.x = acc[i][4] + bv[4]; o1.y = acc[i][5] + bv[5];
    o1.z = acc[i][6] + bv[6]; o1.w = acc[i][7] + bv[7];
    float* Crow = GI + (size_t)(bm + ty * 8 + i) * N3 + n0;
    *(float4*)Crow = o0;
    *(float4*)(Crow + 4) = o1;
  }
}

// ---------------------------------------------------------------------------
// Persistent recurrent kernel. 256 blocks x 256 threads (1 block/CU, all
// co-resident). Wave w owns hidden units {2w, 2w+1} -> 6 rows of W_hh held in
// registers (192 fp32/thread). Per step: stage h (global->LDS via device-scope
// atomics), 192 FMAs, 6 x 64-lane butterfly reduce, gate math on lanes 0/1,
// write h_new to the alternate h buffer, grid barrier (monotonic counter).
// ---------------------------------------------------------------------------
__global__ __launch_bounds__(256, 1)
void gru_recurrent_kernel(const float* __restrict__ Whh,
                          const float* __restrict__ bhh,
                          const float* __restrict__ GI,   // [t1-t0][N3]
                          float* __restrict__ out,        // d_out base
                          float* hbuf,                    // [2][HID]
                          int* counter,
                          int t0, int t1) {
  __shared__ float lds_h[HID];
  const int tid  = threadIdx.x;
  const int lane = tid & 63;
  const int wv   = tid >> 6;
  const int gw   = blockIdx.x * 4 + wv;   // global wave 0..1023
  const int i0   = 2 * gw;

  const int rows[6] = {i0, i0 + 1, HID + i0, HID + i0 + 1, 2 * HID + i0, 2 * HID + i0 + 1};

  // Weights in registers: w[r][jb] covers k = jb*256 + lane*4 + {0..3}
  float4 w[6][8];
#pragma unroll
  for (int r = 0; r < 6; ++r) {
    const float* wr = Whh + (size_t)rows[r] * HID + lane * 4;
#pragma unroll
    for (int jb = 0; jb < 8; ++jb)
      w[r][jb] = *(const float4*)(wr + jb * 256);
  }

  float br = 0.f, bz = 0.f, bn_ = 0.f;
  if (lane < 2) {
    br  = bhh[i0 + lane];
    bz  = bhh[HID + i0 + lane];
    bn_ = bhh[2 * HID + i0 + lane];
  }

  for (int t = t0; t < t1; ++t) {
    const float* hr = hbuf + ((t & 1) ? HID : 0);
    float*       hw = hbuf + ((t & 1) ? 0 : HID);

    // prefetch this step's input-side gates (independent of h)
    float gir = 0.f, giz = 0.f, gin = 0.f;
    if (lane < 2) {
      const float* g = GI + (size_t)(t - t0) * N3;
      gir = g[i0 + lane];
      giz = g[HID + i0 + lane];
      gin = g[2 * HID + i0 + lane];
    }

    // stage h into LDS (device-scope loads: h was written by other XCDs)
#pragma unroll
    for (int c = 0; c < 8; ++c) {
      lds_h[tid * 8 + c] =
          __hip_atomic_load(&hr[tid * 8 + c], __ATOMIC_RELAXED, __HIP_MEMORY_SCOPE_AGENT);
    }
    __syncthreads();

    float acc0 = 0.f, acc1 = 0.f, acc2 = 0.f, acc3 = 0.f, acc4 = 0.f, acc5 = 0.f;
#pragma unroll
    for (int jb = 0; jb < 8; ++jb) {
      float4 hv = *(const float4*)&lds_h[jb * 256 + lane * 4];
      acc0 = fmaf(w[0][jb].x, hv.x, acc0); acc0 = fmaf(w[0][jb].y, hv.y, acc0);
      acc0 = fmaf(w[0][jb].z, hv.z, acc0); acc0 = fmaf(w[0][jb].w, hv.w, acc0);
      acc1 = fmaf(w[1][jb].x, hv.x, acc1); acc1 = fmaf(w[1][jb].y, hv.y, acc1);
      acc1 = fmaf(w[1][jb].z, hv.z, acc1); acc1 = fmaf(w[1][jb].w, hv.w, acc1);
      acc2 = fmaf(w[2][jb].x, hv.x, acc2); acc2 = fmaf(w[2][jb].y, hv.y, acc2);
      acc2 = fmaf(w[2][jb].z, hv.z, acc2); acc2 = fmaf(w[2][jb].w, hv.w, acc2);
      acc3 = fmaf(w[3][jb].x, hv.x, acc3); acc3 = fmaf(w[3][jb].y, hv.y, acc3);
      acc3 = fmaf(w[3][jb].z, hv.z, acc3); acc3 = fmaf(w[3][jb].w, hv.w, acc3);
      acc4 = fmaf(w[4][jb].x, hv.x, acc4); acc4 = fmaf(w[4][jb].y, hv.y, acc4);
      acc4 = fmaf(w[4][jb].z, hv.z, acc4); acc4 = fmaf(w[4][jb].w, hv.w, acc4);
      acc5 = fmaf(w[5][jb].x, hv.x, acc5); acc5 = fmaf(w[5][jb].y, hv.y, acc5);
      acc5 = fmaf(w[5][jb].z, hv.z, acc5); acc5 = fmaf(w[5][jb].w, hv.w, acc5);
    }

#pragma unroll
    for (int off = 1; off < 64; off <<= 1) {
      acc0 += __shfl_xor(acc0, off, 64);
      acc1 += __shfl_xor(acc1, off, 64);
      acc2 += __shfl_xor(acc2, off, 64);
      acc3 += __shfl_xor(acc3, off, 64);
      acc4 += __shfl_xor(acc4, off, 64);
      acc5 += __shfl_xor(acc5, off, 64);
    }

    if (lane < 2) {
      const float dr = lane ? acc1 : acc0;
      const float dz = lane ? acc3 : acc2;
      const float dn = lane ? acc5 : acc4;
      const float r = 1.f / (1.f + __expf(-(gir + dr + br)));
      const float z = 1.f / (1.f + __expf(-(giz + dz + bz)));
      const float n = tanhf(gin + r * (dn + bn_));
      const float hp = lds_h[i0 + lane];
      const float hn = (1.f - z) * n + z * hp;
      out[(size_t)t * HID + i0 + lane] = hn;
      if (t == SEQ - 1) {  // final hidden (returned twice)
        out[(size_t)SEQ * HID + i0 + lane] = hn;
        out[(size_t)SEQ * HID + HID + i0 + lane] = hn;
      }
      __hip_atomic_store(&hw[i0 + lane], hn, __ATOMIC_RELAXED, __HIP_MEMORY_SCOPE_AGENT);
    }

    // grid barrier: monotonic counter, target = NBLK*(t+1)
    __syncthreads();   // also drains this block's h stores (waitcnt before barrier)
    if (tid == 0) {
      __hip_atomic_fetch_add(counter, 1, __ATOMIC_RELEASE, __HIP_MEMORY_SCOPE_AGENT);
      const int target = NBLK * (t + 1);
      while (__hip_atomic_load(counter, __ATOMIC_ACQUIRE, __HIP_MEMORY_SCOPE_AGENT) < target)
        __builtin_amdgcn_s_sleep(1);
    }
    __syncthreads();
  }
}

// ---------------------------------------------------------------------------
extern "C" void kernel_launch(void* const* d_in, const int* in_sizes, int n_in,
                              void* d_out, int out_size, void* d_ws, size_t ws_size,
                              hipStream_t stream) {
  const float* x    = (const float*)d_in[0];
  const float* w_ih = (const float*)d_in[1];
  const float* w_hh = (const float*)d_in[2];
  const float* b_ih = (const float*)d_in[3];
  const float* b_hh = (const float*)d_in[4];
  float* out = (float*)d_out;

  // GI chunk size: shrink if workspace is small (each chunk: chunk*N3 fp32)
  int chunk = SEQ;
  while (chunk > 128 &&
         (size_t)chunk * N3 * 4 + 2 * HID * 4 + 256 > ws_size)
    chunk >>= 1;

  const size_t gi_bytes = (size_t)chunk * N3 * 4;
  float* gi      = (float*)d_ws;
  float* hbuf    = (float*)((char*)d_ws + gi_bytes);
  int*   counter = (int*)((char*)d_ws + gi_bytes + 2 * HID * 4);

  // zero h0 (both buffers) + barrier counter (ws is poisoned 0xAA each call)
  hipMemsetAsync(hbuf, 0, 2 * HID * 4 + 64, stream);

  for (int t0 = 0; t0 < SEQ; t0 += chunk) {
    dim3 ggrid(N3 / BN, chunk / BM);
    gi_gemm_kernel<<<ggrid, 256, 0, stream>>>(x + (size_t)t0 * HID, w_ih, b_ih, gi);
    gru_recurrent_kernel<<<NBLK, 256, 0, stream>>>(w_hh, b_hh, gi, out, hbuf, counter,
                                                   t0, t0 + chunk);
  }
}

// Round 3
// 10190.243 us; speedup vs baseline: 2.7397x; 2.7397x over previous
//
#include <hip/hip_runtime.h>
#include <math.h>

#define HID 2048
#define SEQ 2048
#define N3  6144   // 3*HID
#define NBLK 256

// ---------------------------------------------------------------------------
// GEMM: GI = X @ W_ih^T + b_ih   (fp32, classic 128x128x16 LDS tile, 8x8/thread)
// ---------------------------------------------------------------------------
#define BM 128
#define BN 128
#define BK 16

__global__ __launch_bounds__(256)
void gi_gemm_kernel(const float* __restrict__ X, const float* __restrict__ W,
                    const float* __restrict__ bias, float* __restrict__ GI) {
  __shared__ float As[BK][BM + 4];
  __shared__ float Bs[BK][BN + 4];
  const int tid = threadIdx.x;
  const int bm = blockIdx.y * BM;
  const int bn = blockIdx.x * BN;
  const int tx = tid & 15;
  const int ty = tid >> 4;
  const int lr = tid >> 1;
  const int lk = (tid & 1) * 8;

  float acc[8][8];
#pragma unroll
  for (int i = 0; i < 8; ++i)
#pragma unroll
    for (int j = 0; j < 8; ++j) acc[i][j] = 0.f;

  const float* Arow = X + (size_t)(bm + lr) * HID + lk;
  const float* Brow = W + (size_t)(bn + lr) * HID + lk;

  for (int kc = 0; kc < HID; kc += BK) {
    float4 a0 = *(const float4*)(Arow + kc);
    float4 a1 = *(const float4*)(Arow + kc + 4);
    float4 b0 = *(const float4*)(Brow + kc);
    float4 b1 = *(const float4*)(Brow + kc + 4);
    __syncthreads();
    As[lk + 0][lr] = a0.x; As[lk + 1][lr] = a0.y; As[lk + 2][lr] = a0.z; As[lk + 3][lr] = a0.w;
    As[lk + 4][lr] = a1.x; As[lk + 5][lr] = a1.y; As[lk + 6][lr] = a1.z; As[lk + 7][lr] = a1.w;
    Bs[lk + 0][lr] = b0.x; Bs[lk + 1][lr] = b0.y; Bs[lk + 2][lr] = b0.z; Bs[lk + 3][lr] = b0.w;
    Bs[lk + 4][lr] = b1.x; Bs[lk + 5][lr] = b1.y; Bs[lk + 6][lr] = b1.z; Bs[lk + 7][lr] = b1.w;
    __syncthreads();
#pragma unroll
    for (int kk = 0; kk < BK; ++kk) {
      float4 av0 = *(const float4*)&As[kk][ty * 8];
      float4 av1 = *(const float4*)&As[kk][ty * 8 + 4];
      float4 bv0 = *(const float4*)&Bs[kk][tx * 8];
      float4 bv1 = *(const float4*)&Bs[kk][tx * 8 + 4];
      float a[8] = {av0.x, av0.y, av0.z, av0.w, av1.x, av1.y, av1.z, av1.w};
      float b[8] = {bv0.x, bv0.y, bv0.z, bv0.w, bv1.x, bv1.y, bv1.z, bv1.w};
#pragma unroll
      for (int i = 0; i < 8; ++i)
#pragma unroll
        for (int j = 0; j < 8; ++j)
          acc[i][j] = fmaf(a[i], b[j], acc[i][j]);
    }
  }

  const int n0 = bn + tx * 8;
  float bv[8];
#pragma unroll
  for (int j = 0; j < 8; ++j) bv[j] = bias[n0 + j];
#pragma unroll
  for (int i = 0; i < 8; ++i) {
    float4 o0, o1;
    o0.x = acc[i][0] + bv[0]; o0.y = acc[i][1] + bv[1];
    o0.z = acc[i][2] + bv[2]; o0.w = acc[i][3] + bv[3];
    o1.x = acc[i][4] + bv[4]; o1.y = acc[i][5] + bv[5];
    o1.z = acc[i][6] + bv[6]; o1.w = acc[i][7] + bv[7];
    float* Crow = GI + (size_t)(bm + ty * 8 + i) * N3 + n0;
    *(float4*)Crow = o0;
    *(float4*)(Crow + 4) = o1;
  }
}

// ---------------------------------------------------------------------------
// Persistent recurrent kernel, data-flow synchronized (NO grid barrier).
// h is exchanged as uint64 (epoch<<32 | float bits) pairs, double-buffered:
//   h_t lives in hpair[t&1][*] tagged t. Producers write h_{t+1} tagged t+1
//   into hpair[(t+1)&1] only AFTER reading all of h_t (stage -> syncthreads
//   -> compute -> write), so a tag can never skip past a waiting consumer.
// W_hh pinned in VGPRs (192/thread) via per-scalar opaque asm.
// ---------------------------------------------------------------------------
__device__ __forceinline__ unsigned long long ld_pair(const unsigned long long* p) {
  return __hip_atomic_load(p, __ATOMIC_RELAXED, __HIP_MEMORY_SCOPE_AGENT);
}

__global__ __launch_bounds__(256, 1)
void gru_recurrent_kernel(const float* __restrict__ Whh,
                          const float* __restrict__ bhh,
                          const float* __restrict__ GI,      // [t1-t0][N3]
                          float* __restrict__ out,
                          unsigned long long* hpair,         // [2][HID]
                          int t0, int t1) {
  __shared__ float lds_h[HID];
  const int tid  = threadIdx.x;
  const int lane = tid & 63;
  const int wv   = tid >> 6;
  const int gw   = blockIdx.x * 4 + wv;   // 0..1023
  const int i0   = 2 * gw;

  const int rows[6] = {i0, i0 + 1, HID + i0, HID + i0 + 1, 2 * HID + i0, 2 * HID + i0 + 1};

  // Weights in registers: w[r][jb] covers k = jb*256 + lane*4 + {0..3}
  float4 w[6][8];
#pragma unroll
  for (int r = 0; r < 6; ++r) {
    const float* wr = Whh + (size_t)rows[r] * HID + lane * 4;
#pragma unroll
    for (int jb = 0; jb < 8; ++jb) {
      w[r][jb] = *(const float4*)(wr + jb * 256);
      // opaque per-scalar constraint: force resident VGPRs, forbid remat
      asm volatile("" : "+v"(w[r][jb].x), "+v"(w[r][jb].y),
                        "+v"(w[r][jb].z), "+v"(w[r][jb].w));
    }
  }

  float br = 0.f, bz = 0.f, bn_ = 0.f;
  if (lane < 2) {
    br  = bhh[i0 + lane];
    bz  = bhh[HID + i0 + lane];
    bn_ = bhh[2 * HID + i0 + lane];
  }

  for (int t = t0; t < t1; ++t) {
    // prefetch this step's input-side gates (independent of h)
    float gir = 0.f, giz = 0.f, gin = 0.f;
    if (lane < 2) {
      const float* g = GI + (size_t)(t - t0) * N3;
      gir = g[i0 + lane];
      giz = g[HID + i0 + lane];
      gin = g[2 * HID + i0 + lane];
    }

    // ---- stage h_t: poll tag-carrying pairs, write lane-contiguous float4 ----
    const unsigned long long* hb = hpair + (size_t)(t & 1) * HID;
    const unsigned tag = (unsigned)t;
#pragma unroll
    for (int r = 0; r < 2; ++r) {
      const int base = r * 1024 + tid * 4;
      unsigned long long p0 = ld_pair(hb + base + 0);
      unsigned long long p1 = ld_pair(hb + base + 1);
      unsigned long long p2 = ld_pair(hb + base + 2);
      unsigned long long p3 = ld_pair(hb + base + 3);
      while ((unsigned)(p0 >> 32) != tag) p0 = ld_pair(hb + base + 0);
      while ((unsigned)(p1 >> 32) != tag) p1 = ld_pair(hb + base + 1);
      while ((unsigned)(p2 >> 32) != tag) p2 = ld_pair(hb + base + 2);
      while ((unsigned)(p3 >> 32) != tag) p3 = ld_pair(hb + base + 3);
      float4 v;
      v.x = __uint_as_float((unsigned)p0);
      v.y = __uint_as_float((unsigned)p1);
      v.z = __uint_as_float((unsigned)p2);
      v.w = __uint_as_float((unsigned)p3);
      *(float4*)&lds_h[base] = v;
    }
    __syncthreads();

    // ---- matvec: 6 rows x 2048 ----
    float acc0 = 0.f, acc1 = 0.f, acc2 = 0.f, acc3 = 0.f, acc4 = 0.f, acc5 = 0.f;
#pragma unroll
    for (int jb = 0; jb < 8; ++jb) {
      float4 hv = *(const float4*)&lds_h[jb * 256 + lane * 4];
      acc0 = fmaf(w[0][jb].x, hv.x, acc0); acc0 = fmaf(w[0][jb].y, hv.y, acc0);
      acc0 = fmaf(w[0][jb].z, hv.z, acc0); acc0 = fmaf(w[0][jb].w, hv.w, acc0);
      acc1 = fmaf(w[1][jb].x, hv.x, acc1); acc1 = fmaf(w[1][jb].y, hv.y, acc1);
      acc1 = fmaf(w[1][jb].z, hv.z, acc1); acc1 = fmaf(w[1][jb].w, hv.w, acc1);
      acc2 = fmaf(w[2][jb].x, hv.x, acc2); acc2 = fmaf(w[2][jb].y, hv.y, acc2);
      acc2 = fmaf(w[2][jb].z, hv.z, acc2); acc2 = fmaf(w[2][jb].w, hv.w, acc2);
      acc3 = fmaf(w[3][jb].x, hv.x, acc3); acc3 = fmaf(w[3][jb].y, hv.y, acc3);
      acc3 = fmaf(w[3][jb].z, hv.z, acc3); acc3 = fmaf(w[3][jb].w, hv.w, acc3);
      acc4 = fmaf(w[4][jb].x, hv.x, acc4); acc4 = fmaf(w[4][jb].y, hv.y, acc4);
      acc4 = fmaf(w[4][jb].z, hv.z, acc4); acc4 = fmaf(w[4][jb].w, hv.w, acc4);
      acc5 = fmaf(w[5][jb].x, hv.x, acc5); acc5 = fmaf(w[5][jb].y, hv.y, acc5);
      acc5 = fmaf(w[5][jb].z, hv.z, acc5); acc5 = fmaf(w[5][jb].w, hv.w, acc5);
    }

#pragma unroll
    for (int off = 1; off < 64; off <<= 1) {
      acc0 += __shfl_xor(acc0, off, 64);
      acc1 += __shfl_xor(acc1, off, 64);
      acc2 += __shfl_xor(acc2, off, 64);
      acc3 += __shfl_xor(acc3, off, 64);
      acc4 += __shfl_xor(acc4, off, 64);
      acc5 += __shfl_xor(acc5, off, 64);
    }

    if (lane < 2) {
      const float dr = lane ? acc1 : acc0;
      const float dz = lane ? acc3 : acc2;
      const float dn = lane ? acc5 : acc4;
      const float r = 1.f / (1.f + __expf(-(gir + dr + br)));
      const float z = 1.f / (1.f + __expf(-(giz + dz + bz)));
      const float n = tanhf(gin + r * (dn + bn_));
      const float hp = lds_h[i0 + lane];
      const float hn = (1.f - z) * n + z * hp;
      out[(size_t)t * HID + i0 + lane] = hn;
      if (t == SEQ - 1) {
        out[(size_t)SEQ * HID + i0 + lane] = hn;
        out[(size_t)SEQ * HID + HID + i0 + lane] = hn;
      }
      unsigned long long pk =
          ((unsigned long long)(unsigned)(t + 1) << 32) | __float_as_uint(hn);
      __hip_atomic_store(&hpair[(size_t)((t + 1) & 1) * HID + i0 + lane], pk,
                         __ATOMIC_RELAXED, __HIP_MEMORY_SCOPE_AGENT);
    }
    __syncthreads();  // protect lds_h against next iteration's staging writes
  }
}

// ---------------------------------------------------------------------------
extern "C" void kernel_launch(void* const* d_in, const int* in_sizes, int n_in,
                              void* d_out, int out_size, void* d_ws, size_t ws_size,
                              hipStream_t stream) {
  const float* x    = (const float*)d_in[0];
  const float* w_ih = (const float*)d_in[1];
  const float* w_hh = (const float*)d_in[2];
  const float* b_ih = (const float*)d_in[3];
  const float* b_hh = (const float*)d_in[4];
  float* out = (float*)d_out;

  int chunk = SEQ;
  while (chunk > 128 &&
         (size_t)chunk * N3 * 4 + 2 * HID * 8 + 256 > ws_size)
    chunk >>= 1;

  const size_t gi_bytes = (size_t)chunk * N3 * 4;
  float* gi = (float*)d_ws;
  unsigned long long* hpair = (unsigned long long*)((char*)d_ws + gi_bytes);

  // h_0 = 0.0f tagged epoch 0 == all-zero bytes; clears both buffers
  hipMemsetAsync(hpair, 0, 2 * HID * 8, stream);

  for (int t0 = 0; t0 < SEQ; t0 += chunk) {
    dim3 ggrid(N3 / BN, chunk / BM);
    gi_gemm_kernel<<<ggrid, 256, 0, stream>>>(x + (size_t)t0 * HID, w_ih, b_ih, gi);
    gru_recurrent_kernel<<<NBLK, 256, 0, stream>>>(w_hh, b_hh, gi, out, hpair,
                                                   t0, t0 + chunk);
  }
}

// Round 4
// 8946.909 us; speedup vs baseline: 3.1204x; 1.1390x over previous
//
#include <hip/hip_runtime.h>
#include <math.h>

#define HID 2048
#define SEQ 2048
#define N3  6144   // 3*HID
#define NBLK 256

// ---------------------------------------------------------------------------
// GEMM: GI = X @ W_ih^T + b_ih   (fp32, classic 128x128x16 LDS tile, 8x8/thread)
// ---------------------------------------------------------------------------
#define BM 128
#define BN 128
#define BK 16

__global__ __launch_bounds__(256)
void gi_gemm_kernel(const float* __restrict__ X, const float* __restrict__ W,
                    const float* __restrict__ bias, float* __restrict__ GI) {
  __shared__ float As[BK][BM + 4];
  __shared__ float Bs[BK][BN + 4];
  const int tid = threadIdx.x;
  const int bm = blockIdx.y * BM;
  const int bn = blockIdx.x * BN;
  const int tx = tid & 15;
  const int ty = tid >> 4;
  const int lr = tid >> 1;
  const int lk = (tid & 1) * 8;

  float acc[8][8];
#pragma unroll
  for (int i = 0; i < 8; ++i)
#pragma unroll
    for (int j = 0; j < 8; ++j) acc[i][j] = 0.f;

  const float* Arow = X + (size_t)(bm + lr) * HID + lk;
  const float* Brow = W + (size_t)(bn + lr) * HID + lk;

  for (int kc = 0; kc < HID; kc += BK) {
    float4 a0 = *(const float4*)(Arow + kc);
    float4 a1 = *(const float4*)(Arow + kc + 4);
    float4 b0 = *(const float4*)(Brow + kc);
    float4 b1 = *(const float4*)(Brow + kc + 4);
    __syncthreads();
    As[lk + 0][lr] = a0.x; As[lk + 1][lr] = a0.y; As[lk + 2][lr] = a0.z; As[lk + 3][lr] = a0.w;
    As[lk + 4][lr] = a1.x; As[lk + 5][lr] = a1.y; As[lk + 6][lr] = a1.z; As[lk + 7][lr] = a1.w;
    Bs[lk + 0][lr] = b0.x; Bs[lk + 1][lr] = b0.y; Bs[lk + 2][lr] = b0.z; Bs[lk + 3][lr] = b0.w;
    Bs[lk + 4][lr] = b1.x; Bs[lk + 5][lr] = b1.y; Bs[lk + 6][lr] = b1.z; Bs[lk + 7][lr] = b1.w;
    __syncthreads();
#pragma unroll
    for (int kk = 0; kk < BK; ++kk) {
      float4 av0 = *(const float4*)&As[kk][ty * 8];
      float4 av1 = *(const float4*)&As[kk][ty * 8 + 4];
      float4 bv0 = *(const float4*)&Bs[kk][tx * 8];
      float4 bv1 = *(const float4*)&Bs[kk][tx * 8 + 4];
      float a[8] = {av0.x, av0.y, av0.z, av0.w, av1.x, av1.y, av1.z, av1.w};
      float b[8] = {bv0.x, bv0.y, bv0.z, bv0.w, bv1.x, bv1.y, bv1.z, bv1.w};
#pragma unroll
      for (int i = 0; i < 8; ++i)
#pragma unroll
        for (int j = 0; j < 8; ++j)
          acc[i][j] = fmaf(a[i], b[j], acc[i][j]);
    }
  }

  const int n0 = bn + tx * 8;
  float bv[8];
#pragma unroll
  for (int j = 0; j < 8; ++j) bv[j] = bias[n0 + j];
#pragma unroll
  for (int i = 0; i < 8; ++i) {
    float4 o0, o1;
    o0.x = acc[i][0] + bv[0]; o0.y = acc[i][1] + bv[1];
    o0.z = acc[i][2] + bv[2]; o0.w = acc[i][3] + bv[3];
    o1.x = acc[i][4] + bv[4]; o1.y = acc[i][5] + bv[5];
    o1.z = acc[i][6] + bv[6]; o1.w = acc[i][7] + bv[7];
    float* Crow = GI + (size_t)(bm + ty * 8 + i) * N3 + n0;
    *(float4*)Crow = o0;
    *(float4*)(Crow + 4) = o1;
  }
}

// ---------------------------------------------------------------------------
// Persistent recurrent kernel, data-flow synchronized (NO grid barrier).
// h is exchanged as uint64 (epoch<<32 | float bits) pairs, double-buffered.
// W_hh pinned in AGPRs (192/thread) via per-scalar "+a" opaque asm — AGPRs are
// uncontended in the unified gfx950 file, so the allocator keeps them resident
// (the R3 "+v" variant spilled and re-streamed 48 MB/step from L3).
// ---------------------------------------------------------------------------
__device__ __forceinline__ unsigned long long ld_pair(const unsigned long long* p) {
  return __hip_atomic_load(p, __ATOMIC_RELAXED, __HIP_MEMORY_SCOPE_AGENT);
}

__global__ __launch_bounds__(256, 1)
void gru_recurrent_kernel(const float* __restrict__ Whh,
                          const float* __restrict__ bhh,
                          const float* __restrict__ GI,      // [t1-t0][N3]
                          float* __restrict__ out,
                          unsigned long long* hpair,         // [2][HID]
                          int t0, int t1) {
  __shared__ float lds_h[HID];
  const int tid  = threadIdx.x;
  const int lane = tid & 63;
  const int wv   = tid >> 6;
  const int gw   = blockIdx.x * 4 + wv;   // 0..1023
  const int i0   = 2 * gw;

  const int rows[6] = {i0, i0 + 1, HID + i0, HID + i0 + 1, 2 * HID + i0, 2 * HID + i0 + 1};

  // Weights pinned in AGPRs: w[r][jb] covers k = jb*256 + lane*4 + {0..3}
  float4 w[6][8];
#pragma unroll
  for (int r = 0; r < 6; ++r) {
    const float* wr = Whh + (size_t)rows[r] * HID + lane * 4;
#pragma unroll
    for (int jb = 0; jb < 8; ++jb) {
      w[r][jb] = *(const float4*)(wr + jb * 256);
      // opaque per-scalar "+a": park each weight in an AGPR, forbid remat/spill
      asm volatile("" : "+a"(w[r][jb].x), "+a"(w[r][jb].y),
                        "+a"(w[r][jb].z), "+a"(w[r][jb].w));
    }
  }

  float br = 0.f, bz = 0.f, bn_ = 0.f;
  if (lane < 2) {
    br  = bhh[i0 + lane];
    bz  = bhh[HID + i0 + lane];
    bn_ = bhh[2 * HID + i0 + lane];
  }

  for (int t = t0; t < t1; ++t) {
    // prefetch this step's input-side gates (independent of h)
    float gir = 0.f, giz = 0.f, gin = 0.f;
    if (lane < 2) {
      const float* g = GI + (size_t)(t - t0) * N3;
      gir = g[i0 + lane];
      giz = g[HID + i0 + lane];
      gin = g[2 * HID + i0 + lane];
    }

    // ---- stage h_t: poll tag-carrying pairs, write lane-contiguous float4 ----
    const unsigned long long* hb = hpair + (size_t)(t & 1) * HID;
    const unsigned tag = (unsigned)t;
#pragma unroll
    for (int r = 0; r < 2; ++r) {
      const int base = r * 1024 + tid * 4;
      unsigned long long p0 = ld_pair(hb + base + 0);
      unsigned long long p1 = ld_pair(hb + base + 1);
      unsigned long long p2 = ld_pair(hb + base + 2);
      unsigned long long p3 = ld_pair(hb + base + 3);
      while ((unsigned)(p0 >> 32) != tag) p0 = ld_pair(hb + base + 0);
      while ((unsigned)(p1 >> 32) != tag) p1 = ld_pair(hb + base + 1);
      while ((unsigned)(p2 >> 32) != tag) p2 = ld_pair(hb + base + 2);
      while ((unsigned)(p3 >> 32) != tag) p3 = ld_pair(hb + base + 3);
      float4 v;
      v.x = __uint_as_float((unsigned)p0);
      v.y = __uint_as_float((unsigned)p1);
      v.z = __uint_as_float((unsigned)p2);
      v.w = __uint_as_float((unsigned)p3);
      *(float4*)&lds_h[base] = v;
    }
    __syncthreads();

    // ---- matvec: 6 rows x 2048 (weights sourced from AGPRs) ----
    float acc0 = 0.f, acc1 = 0.f, acc2 = 0.f, acc3 = 0.f, acc4 = 0.f, acc5 = 0.f;
#pragma unroll
    for (int jb = 0; jb < 8; ++jb) {
      float4 hv = *(const float4*)&lds_h[jb * 256 + lane * 4];
      acc0 = fmaf(w[0][jb].x, hv.x, acc0); acc0 = fmaf(w[0][jb].y, hv.y, acc0);
      acc0 = fmaf(w[0][jb].z, hv.z, acc0); acc0 = fmaf(w[0][jb].w, hv.w, acc0);
      acc1 = fmaf(w[1][jb].x, hv.x, acc1); acc1 = fmaf(w[1][jb].y, hv.y, acc1);
      acc1 = fmaf(w[1][jb].z, hv.z, acc1); acc1 = fmaf(w[1][jb].w, hv.w, acc1);
      acc2 = fmaf(w[2][jb].x, hv.x, acc2); acc2 = fmaf(w[2][jb].y, hv.y, acc2);
      acc2 = fmaf(w[2][jb].z, hv.z, acc2); acc2 = fmaf(w[2][jb].w, hv.w, acc2);
      acc3 = fmaf(w[3][jb].x, hv.x, acc3); acc3 = fmaf(w[3][jb].y, hv.y, acc3);
      acc3 = fmaf(w[3][jb].z, hv.z, acc3); acc3 = fmaf(w[3][jb].w, hv.w, acc3);
      acc4 = fmaf(w[4][jb].x, hv.x, acc4); acc4 = fmaf(w[4][jb].y, hv.y, acc4);
      acc4 = fmaf(w[4][jb].z, hv.z, acc4); acc4 = fmaf(w[4][jb].w, hv.w, acc4);
      acc5 = fmaf(w[5][jb].x, hv.x, acc5); acc5 = fmaf(w[5][jb].y, hv.y, acc5);
      acc5 = fmaf(w[5][jb].z, hv.z, acc5); acc5 = fmaf(w[5][jb].w, hv.w, acc5);
    }

#pragma unroll
    for (int off = 1; off < 64; off <<= 1) {
      acc0 += __shfl_xor(acc0, off, 64);
      acc1 += __shfl_xor(acc1, off, 64);
      acc2 += __shfl_xor(acc2, off, 64);
      acc3 += __shfl_xor(acc3, off, 64);
      acc4 += __shfl_xor(acc4, off, 64);
      acc5 += __shfl_xor(acc5, off, 64);
    }

    if (lane < 2) {
      const float dr = lane ? acc1 : acc0;
      const float dz = lane ? acc3 : acc2;
      const float dn = lane ? acc5 : acc4;
      const float r = 1.f / (1.f + __expf(-(gir + dr + br)));
      const float z = 1.f / (1.f + __expf(-(giz + dz + bz)));
      const float n = tanhf(gin + r * (dn + bn_));
      const float hp = lds_h[i0 + lane];
      const float hn = (1.f - z) * n + z * hp;
      out[(size_t)t * HID + i0 + lane] = hn;
      if (t == SEQ - 1) {
        out[(size_t)SEQ * HID + i0 + lane] = hn;
        out[(size_t)SEQ * HID + HID + i0 + lane] = hn;
      }
      unsigned long long pk =
          ((unsigned long long)(unsigned)(t + 1) << 32) | __float_as_uint(hn);
      __hip_atomic_store(&hpair[(size_t)((t + 1) & 1) * HID + i0 + lane], pk,
                         __ATOMIC_RELAXED, __HIP_MEMORY_SCOPE_AGENT);
    }
    __syncthreads();  // protect lds_h against next iteration's staging writes
  }
}

// ---------------------------------------------------------------------------
extern "C" void kernel_launch(void* const* d_in, const int* in_sizes, int n_in,
                              void* d_out, int out_size, void* d_ws, size_t ws_size,
                              hipStream_t stream) {
  const float* x    = (const float*)d_in[0];
  const float* w_ih = (const float*)d_in[1];
  const float* w_hh = (const float*)d_in[2];
  const float* b_ih = (const float*)d_in[3];
  const float* b_hh = (const float*)d_in[4];
  float* out = (float*)d_out;

  int chunk = SEQ;
  while (chunk > 128 &&
         (size_t)chunk * N3 * 4 + 2 * HID * 8 + 256 > ws_size)
    chunk >>= 1;

  const size_t gi_bytes = (size_t)chunk * N3 * 4;
  float* gi = (float*)d_ws;
  unsigned long long* hpair = (unsigned long long*)((char*)d_ws + gi_bytes);

  // h_0 = 0.0f tagged epoch 0 == all-zero bytes; clears both buffers
  hipMemsetAsync(hpair, 0, 2 * HID * 8, stream);

  for (int t0 = 0; t0 < SEQ; t0 += chunk) {
    dim3 ggrid(N3 / BN, chunk / BM);
    gi_gemm_kernel<<<ggrid, 256, 0, stream>>>(x + (size_t)t0 * HID, w_ih, b_ih, gi);
    gru_recurrent_kernel<<<NBLK, 256, 0, stream>>>(w_hh, b_hh, gi, out, hpair,
                                                   t0, t0 + chunk);
  }
}

// Round 6
// 8148.663 us; speedup vs baseline: 3.4261x; 1.0980x over previous
//
#include <hip/hip_runtime.h>
#include <math.h>

#define HID 2048
#define SEQ 2048
#define N3  6144   // 3*HID
#define NBLK 256

// ---------------------------------------------------------------------------
// GEMM: GI = X @ W_ih^T + b_ih   (fp32, classic 128x128x16 LDS tile, 8x8/thread)
// ---------------------------------------------------------------------------
#define BM 128
#define BN 128
#define BK 16

__global__ __launch_bounds__(256)
void gi_gemm_kernel(const float* __restrict__ X, const float* __restrict__ W,
                    const float* __restrict__ bias, float* __restrict__ GI) {
  __shared__ float As[BK][BM + 4];
  __shared__ float Bs[BK][BN + 4];
  const int tid = threadIdx.x;
  const int bm = blockIdx.y * BM;
  const int bn = blockIdx.x * BN;
  const int tx = tid & 15;
  const int ty = tid >> 4;
  const int lr = tid >> 1;
  const int lk = (tid & 1) * 8;

  float acc[8][8];
#pragma unroll
  for (int i = 0; i < 8; ++i)
#pragma unroll
    for (int j = 0; j < 8; ++j) acc[i][j] = 0.f;

  const float* Arow = X + (size_t)(bm + lr) * HID + lk;
  const float* Brow = W + (size_t)(bn + lr) * HID + lk;

  for (int kc = 0; kc < HID; kc += BK) {
    float4 a0 = *(const float4*)(Arow + kc);
    float4 a1 = *(const float4*)(Arow + kc + 4);
    float4 b0 = *(const float4*)(Brow + kc);
    float4 b1 = *(const float4*)(Brow + kc + 4);
    __syncthreads();
    As[lk + 0][lr] = a0.x; As[lk + 1][lr] = a0.y; As[lk + 2][lr] = a0.z; As[lk + 3][lr] = a0.w;
    As[lk + 4][lr] = a1.x; As[lk + 5][lr] = a1.y; As[lk + 6][lr] = a1.z; As[lk + 7][lr] = a1.w;
    Bs[lk + 0][lr] = b0.x; Bs[lk + 1][lr] = b0.y; Bs[lk + 2][lr] = b0.z; Bs[lk + 3][lr] = b0.w;
    Bs[lk + 4][lr] = b1.x; Bs[lk + 5][lr] = b1.y; Bs[lk + 6][lr] = b1.z; Bs[lk + 7][lr] = b1.w;
    __syncthreads();
#pragma unroll
    for (int kk = 0; kk < BK; ++kk) {
      float4 av0 = *(const float4*)&As[kk][ty * 8];
      float4 av1 = *(const float4*)&As[kk][ty * 8 + 4];
      float4 bv0 = *(const float4*)&Bs[kk][tx * 8];
      float4 bv1 = *(const float4*)&Bs[kk][tx * 8 + 4];
      float a[8] = {av0.x, av0.y, av0.z, av0.w, av1.x, av1.y, av1.z, av1.w};
      float b[8] = {bv0.x, bv0.y, bv0.z, bv0.w, bv1.x, bv1.y, bv1.z, bv1.w};
#pragma unroll
      for (int i = 0; i < 8; ++i)
#pragma unroll
        for (int j = 0; j < 8; ++j)
          acc[i][j] = fmaf(a[i], b[j], acc[i][j]);
    }
  }

  const int n0 = bn + tx * 8;
  float bv[8];
#pragma unroll
  for (int j = 0; j < 8; ++j) bv[j] = bias[n0 + j];
#pragma unroll
  for (int i = 0; i < 8; ++i) {
    float4 o0, o1;
    o0.x = acc[i][0] + bv[0]; o0.y = acc[i][1] + bv[1];
    o0.z = acc[i][2] + bv[2]; o0.w = acc[i][3] + bv[3];
    o1.x = acc[i][4] + bv[4]; o1.y = acc[i][5] + bv[5];
    o1.z = acc[i][6] + bv[6]; o1.w = acc[i][7] + bv[7];
    float* Crow = GI + (size_t)(bm + ty * 8 + i) * N3 + n0;
    *(float4*)Crow = o0;
    *(float4*)(Crow + 4) = o1;
  }
}

// ---------------------------------------------------------------------------
// Persistent recurrent kernel, data-flow synchronized.
//  - batched-retry poll: all 8 tag-pairs checked together, parallel re-issue
//  - DPP wave reduction (row_shr 1/2/4/8 + row_bcast 15/31 -> lane 63)
//  - double-buffered LDS, single __syncthreads per step
//  - GI gate inputs prefetched one step ahead
//  - W_hh pinned in AGPRs via per-scalar "+a" opaque asm
// ---------------------------------------------------------------------------
__device__ __forceinline__ unsigned long long ld_pair(const unsigned long long* p) {
  return __hip_atomic_load(p, __ATOMIC_RELAXED, __HIP_MEMORY_SCOPE_AGENT);
}

template <int CTRL, int ROW_MASK>
__device__ __forceinline__ float dpp_add(float x) {
  int y = __builtin_amdgcn_update_dpp(0, __float_as_uint(x), CTRL, ROW_MASK, 0xf, true);
  return x + __uint_as_float(y);
}

// full 64-lane sum -> wave-uniform scalar (via lane 63 readlane)
__device__ __forceinline__ float wave_sum(float x) {
  x = dpp_add<0x111, 0xf>(x);  // row_shr:1
  x = dpp_add<0x112, 0xf>(x);  // row_shr:2
  x = dpp_add<0x114, 0xf>(x);  // row_shr:4
  x = dpp_add<0x118, 0xf>(x);  // row_shr:8
  x = dpp_add<0x142, 0xa>(x);  // row_bcast:15, rows 1,3
  x = dpp_add<0x143, 0xc>(x);  // row_bcast:31, rows 2,3
  return __uint_as_float(__builtin_amdgcn_readlane(__float_as_uint(x), 63));
}

__device__ __forceinline__ float rlane(float x, int l) {
  return __uint_as_float(__builtin_amdgcn_readlane(__float_as_uint(x), l));
}

__device__ __forceinline__ float sigf(float x) {
  return __builtin_amdgcn_rcpf(1.f + __expf(-x));
}
__device__ __forceinline__ float tanhfast(float x) {
  return 1.f - 2.f * __builtin_amdgcn_rcpf(1.f + __expf(2.f * x));
}

__global__ __launch_bounds__(256, 1)
void gru_recurrent_kernel(const float* __restrict__ Whh,
                          const float* __restrict__ bhh,
                          const float* __restrict__ GI,      // [t1-t0][N3]
                          float* __restrict__ out,
                          unsigned long long* hpair,         // [2][HID]
                          int t0, int t1) {
  __shared__ float lds_h[2][HID];
  const int tid  = threadIdx.x;
  const int lane = tid & 63;
  const int wv   = tid >> 6;
  const int gw   = blockIdx.x * 4 + wv;   // 0..1023
  const int i0   = 2 * gw;

  const int rows[6] = {i0, i0 + 1, HID + i0, HID + i0 + 1, 2 * HID + i0, 2 * HID + i0 + 1};

  // Weights pinned in AGPRs: w[r][jb] covers k = jb*256 + lane*4 + {0..3}
  float4 w[6][8];
#pragma unroll
  for (int r = 0; r < 6; ++r) {
    const float* wr = Whh + (size_t)rows[r] * HID + lane * 4;
#pragma unroll
    for (int jb = 0; jb < 8; ++jb) {
      w[r][jb] = *(const float4*)(wr + jb * 256);
      asm volatile("" : "+a"(w[r][jb].x), "+a"(w[r][jb].y),
                        "+a"(w[r][jb].z), "+a"(w[r][jb].w));
    }
  }

  // wave-uniform biases for the wave's two units
  float br0, br1, bz0, bz1, bn0, bn1;
  {
    float a = 0.f, b = 0.f, c = 0.f;
    if (lane < 2) {
      a = bhh[i0 + lane];
      b = bhh[HID + i0 + lane];
      c = bhh[2 * HID + i0 + lane];
    }
    br0 = rlane(a, 0); br1 = rlane(a, 1);
    bz0 = rlane(b, 0); bz1 = rlane(b, 1);
    bn0 = rlane(c, 0); bn1 = rlane(c, 1);
  }

  // GI prefetch for first step (lanes 0,1 hold unit0/unit1 values)
  float gr = 0.f, gz = 0.f, gn = 0.f;
  if (lane < 2) {
    const float* g = GI;
    gr = g[i0 + lane];
    gz = g[HID + i0 + lane];
    gn = g[2 * HID + i0 + lane];
  }

  const int b0 = tid * 4;

  for (int t = t0; t < t1; ++t) {
    // prefetch NEXT step's input gates (independent of h; hides GI HBM latency)
    float pr = 0.f, pz = 0.f, pn = 0.f;
    if (t + 1 < t1 && lane < 2) {
      const float* g = GI + (size_t)(t + 1 - t0) * N3;
      pr = g[i0 + lane];
      pz = g[HID + i0 + lane];
      pn = g[2 * HID + i0 + lane];
    }

    // ---- batched-retry poll of this thread's 8 tag-pairs ----
    const unsigned long long* hb = hpair + (size_t)(t & 1) * HID;
    const unsigned tag = (unsigned)t;
    unsigned long long p[8];
#pragma unroll
    for (int i = 0; i < 4; ++i) p[i] = ld_pair(hb + b0 + i);
#pragma unroll
    for (int i = 0; i < 4; ++i) p[4 + i] = ld_pair(hb + 1024 + b0 + i);
    for (;;) {
      int stale = 0;
#pragma unroll
      for (int i = 0; i < 8; ++i)
        stale |= ((unsigned)(p[i] >> 32) != tag) ? (1 << i) : 0;
      if (!stale) break;
#pragma unroll
      for (int i = 0; i < 4; ++i)
        if (stale & (1 << i)) p[i] = ld_pair(hb + b0 + i);
#pragma unroll
      for (int i = 0; i < 4; ++i)
        if (stale & (1 << (4 + i))) p[4 + i] = ld_pair(hb + 1024 + b0 + i);
    }

    float* lc = lds_h[t & 1];
    {
      float4 v0, v1;
      v0.x = __uint_as_float((unsigned)p[0]);
      v0.y = __uint_as_float((unsigned)p[1]);
      v0.z = __uint_as_float((unsigned)p[2]);
      v0.w = __uint_as_float((unsigned)p[3]);
      v1.x = __uint_as_float((unsigned)p[4]);
      v1.y = __uint_as_float((unsigned)p[5]);
      v1.z = __uint_as_float((unsigned)p[6]);
      v1.w = __uint_as_float((unsigned)p[7]);
      *(float4*)&lc[b0] = v0;
      *(float4*)&lc[1024 + b0] = v1;
    }
    __syncthreads();

    // ---- matvec: 6 rows x 2048 (weights in AGPRs) ----
    float acc0 = 0.f, acc1 = 0.f, acc2 = 0.f, acc3 = 0.f, acc4 = 0.f, acc5 = 0.f;
#pragma unroll
    for (int jb = 0; jb < 8; ++jb) {
      float4 hv = *(const float4*)&lc[jb * 256 + lane * 4];
      acc0 = fmaf(w[0][jb].x, hv.x, acc0); acc0 = fmaf(w[0][jb].y, hv.y, acc0);
      acc0 = fmaf(w[0][jb].z, hv.z, acc0); acc0 = fmaf(w[0][jb].w, hv.w, acc0);
      acc1 = fmaf(w[1][jb].x, hv.x, acc1); acc1 = fmaf(w[1][jb].y, hv.y, acc1);
      acc1 = fmaf(w[1][jb].z, hv.z, acc1); acc1 = fmaf(w[1][jb].w, hv.w, acc1);
      acc2 = fmaf(w[2][jb].x, hv.x, acc2); acc2 = fmaf(w[2][jb].y, hv.y, acc2);
      acc2 = fmaf(w[2][jb].z, hv.z, acc2); acc2 = fmaf(w[2][jb].w, hv.w, acc2);
      acc3 = fmaf(w[3][jb].x, hv.x, acc3); acc3 = fmaf(w[3][jb].y, hv.y, acc3);
      acc3 = fmaf(w[3][jb].z, hv.z, acc3); acc3 = fmaf(w[3][jb].w, hv.w, acc3);
      acc4 = fmaf(w[4][jb].x, hv.x, acc4); acc4 = fmaf(w[4][jb].y, hv.y, acc4);
      acc4 = fmaf(w[4][jb].z, hv.z, acc4); acc4 = fmaf(w[4][jb].w, hv.w, acc4);
      acc5 = fmaf(w[5][jb].x, hv.x, acc5); acc5 = fmaf(w[5][jb].y, hv.y, acc5);
      acc5 = fmaf(w[5][jb].z, hv.z, acc5); acc5 = fmaf(w[5][jb].w, hv.w, acc5);
    }

    // ---- DPP reduce -> wave-uniform sums ----
    const float sr0 = wave_sum(acc0), sr1 = wave_sum(acc1);
    const float sz0 = wave_sum(acc2), sz1 = wave_sum(acc3);
    const float sn0 = wave_sum(acc4), sn1 = wave_sum(acc5);

    // wave-uniform gate math for both units
    const float gr0 = rlane(gr, 0), gr1 = rlane(gr, 1);
    const float gz0 = rlane(gz, 0), gz1 = rlane(gz, 1);
    const float gn0 = rlane(gn, 0), gn1 = rlane(gn, 1);

    const float r0 = sigf(gr0 + sr0 + br0);
    const float r1 = sigf(gr1 + sr1 + br1);
    const float z0 = sigf(gz0 + sz0 + bz0);
    const float z1 = sigf(gz1 + sz1 + bz1);
    const float n0 = tanhfast(gn0 + r0 * (sn0 + bn0));
    const float n1 = tanhfast(gn1 + r1 * (sn1 + bn1));
    const float hp0 = lc[i0], hp1 = lc[i0 + 1];   // uniform-address LDS broadcast
    const float hn0 = (1.f - z0) * n0 + z0 * hp0;
    const float hn1 = (1.f - z1) * n1 + z1 * hp1;

    const float hn = lane ? hn1 : hn0;
    if (lane < 2) {
      // h-propagation store FIRST (critical path), out stores after
      unsigned long long pk =
          ((unsigned long long)(unsigned)(t + 1) << 32) | __float_as_uint(hn);
      __hip_atomic_store(&hpair[(size_t)((t + 1) & 1) * HID + i0 + lane], pk,
                         __ATOMIC_RELAXED, __HIP_MEMORY_SCOPE_AGENT);
      out[(size_t)t * HID + i0 + lane] = hn;
      if (t == SEQ - 1) {
        out[(size_t)SEQ * HID + i0 + lane] = hn;
        out[(size_t)SEQ * HID + HID + i0 + lane] = hn;
      }
    }

    gr = pr; gz = pz; gn = pn;
    // no end-of-loop barrier: LDS is double-buffered; the post-staging
    // __syncthreads of the NEXT iteration orders writes to lds_h[(t+1)&1]
  }
}

// ---------------------------------------------------------------------------
extern "C" void kernel_launch(void* const* d_in, const int* in_sizes, int n_in,
                              void* d_out, int out_size, void* d_ws, size_t ws_size,
                              hipStream_t stream) {
  const float* x    = (const float*)d_in[0];
  const float* w_ih = (const float*)d_in[1];
  const float* w_hh = (const float*)d_in[2];
  const float* b_ih = (const float*)d_in[3];
  const float* b_hh = (const float*)d_in[4];
  float* out = (float*)d_out;

  int chunk = SEQ;
  while (chunk > 128 &&
         (size_t)chunk * N3 * 4 + 2 * HID * 8 + 256 > ws_size)
    chunk >>= 1;

  const size_t gi_bytes = (size_t)chunk * N3 * 4;
  float* gi = (float*)d_ws;
  unsigned long long* hpair = (unsigned long long*)((char*)d_ws + gi_bytes);

  // h_0 = 0.0f tagged epoch 0 == all-zero bytes; clears both buffers
  (void)hipMemsetAsync(hpair, 0, 2 * HID * 8, stream);

  for (int t0 = 0; t0 < SEQ; t0 += chunk) {
    dim3 ggrid(N3 / BN, chunk / BM);
    gi_gemm_kernel<<<ggrid, 256, 0, stream>>>(x + (size_t)t0 * HID, w_ih, b_ih, gi);
    gru_recurrent_kernel<<<NBLK, 256, 0, stream>>>(w_hh, b_hh, gi, out, hpair,
                                                   t0, t0 + chunk);
  }
}

// Round 7
// 7608.006 us; speedup vs baseline: 3.6696x; 1.0711x over previous
//
#include <hip/hip_runtime.h>
#include <math.h>

#define HID 2048
#define SEQ 2048
#define N3  6144   // 3*HID
#define NBLK 256
#define NREG 8     // replicated exchange regions (contention spread)

// ---------------------------------------------------------------------------
// GEMM: GI = X @ W_ih^T + b_ih   (fp32, classic 128x128x16 LDS tile, 8x8/thread)
// ---------------------------------------------------------------------------
#define BM 128
#define BN 128
#define BK 16

__global__ __launch_bounds__(256)
void gi_gemm_kernel(const float* __restrict__ X, const float* __restrict__ W,
                    const float* __restrict__ bias, float* __restrict__ GI) {
  __shared__ float As[BK][BM + 4];
  __shared__ float Bs[BK][BN + 4];
  const int tid = threadIdx.x;
  const int bm = blockIdx.y * BM;
  const int bn = blockIdx.x * BN;
  const int tx = tid & 15;
  const int ty = tid >> 4;
  const int lr = tid >> 1;
  const int lk = (tid & 1) * 8;

  float acc[8][8];
#pragma unroll
  for (int i = 0; i < 8; ++i)
#pragma unroll
    for (int j = 0; j < 8; ++j) acc[i][j] = 0.f;

  const float* Arow = X + (size_t)(bm + lr) * HID + lk;
  const float* Brow = W + (size_t)(bn + lr) * HID + lk;

  for (int kc = 0; kc < HID; kc += BK) {
    float4 a0 = *(const float4*)(Arow + kc);
    float4 a1 = *(const float4*)(Arow + kc + 4);
    float4 b0 = *(const float4*)(Brow + kc);
    float4 b1 = *(const float4*)(Brow + kc + 4);
    __syncthreads();
    As[lk + 0][lr] = a0.x; As[lk + 1][lr] = a0.y; As[lk + 2][lr] = a0.z; As[lk + 3][lr] = a0.w;
    As[lk + 4][lr] = a1.x; As[lk + 5][lr] = a1.y; As[lk + 6][lr] = a1.z; As[lk + 7][lr] = a1.w;
    Bs[lk + 0][lr] = b0.x; Bs[lk + 1][lr] = b0.y; Bs[lk + 2][lr] = b0.z; Bs[lk + 3][lr] = b0.w;
    Bs[lk + 4][lr] = b1.x; Bs[lk + 5][lr] = b1.y; Bs[lk + 6][lr] = b1.z; Bs[lk + 7][lr] = b1.w;
    __syncthreads();
#pragma unroll
    for (int kk = 0; kk < BK; ++kk) {
      float4 av0 = *(const float4*)&As[kk][ty * 8];
      float4 av1 = *(const float4*)&As[kk][ty * 8 + 4];
      float4 bv0 = *(const float4*)&Bs[kk][tx * 8];
      float4 bv1 = *(const float4*)&Bs[kk][tx * 8 + 4];
      float a[8] = {av0.x, av0.y, av0.z, av0.w, av1.x, av1.y, av1.z, av1.w};
      float b[8] = {bv0.x, bv0.y, bv0.z, bv0.w, bv1.x, bv1.y, bv1.z, bv1.w};
#pragma unroll
      for (int i = 0; i < 8; ++i)
#pragma unroll
        for (int j = 0; j < 8; ++j)
          acc[i][j] = fmaf(a[i], b[j], acc[i][j]);
    }
  }

  const int n0 = bn + tx * 8;
  float bv[8];
#pragma unroll
  for (int j = 0; j < 8; ++j) bv[j] = bias[n0 + j];
#pragma unroll
  for (int i = 0; i < 8; ++i) {
    float4 o0, o1;
    o0.x = acc[i][0] + bv[0]; o0.y = acc[i][1] + bv[1];
    o0.z = acc[i][2] + bv[2]; o0.w = acc[i][3] + bv[3];
    o1.x = acc[i][4] + bv[4]; o1.y = acc[i][5] + bv[5];
    o1.z = acc[i][6] + bv[6]; o1.w = acc[i][7] + bv[7];
    float* Crow = GI + (size_t)(bm + ty * 8 + i) * N3 + n0;
    *(float4*)Crow = o0;
    *(float4*)(Crow + 4) = o1;
  }
}

// ---------------------------------------------------------------------------
// Persistent recurrent kernel, data-flow synchronized via 8-way REPLICATED
// tag-pair regions: producers store {tag|h} to all 8 regions; each block polls
// only region blockIdx&7 -> 8x fewer L3 line-requests per hot line.
// GI prefetch issued AFTER staging (polls never drain an HBM load).
// out row t-1 written by ONE designated block from staged registers.
// W_hh pinned in AGPRs; DPP wave reduce; double-buffered LDS.
// ---------------------------------------------------------------------------
__device__ __forceinline__ unsigned long long ld_pair(const unsigned long long* p) {
  return __hip_atomic_load(p, __ATOMIC_RELAXED, __HIP_MEMORY_SCOPE_AGENT);
}

template <int CTRL, int ROW_MASK>
__device__ __forceinline__ float dpp_add(float x) {
  int y = __builtin_amdgcn_update_dpp(0, __float_as_uint(x), CTRL, ROW_MASK, 0xf, true);
  return x + __uint_as_float(y);
}

__device__ __forceinline__ float wave_sum(float x) {
  x = dpp_add<0x111, 0xf>(x);  // row_shr:1
  x = dpp_add<0x112, 0xf>(x);  // row_shr:2
  x = dpp_add<0x114, 0xf>(x);  // row_shr:4
  x = dpp_add<0x118, 0xf>(x);  // row_shr:8
  x = dpp_add<0x142, 0xa>(x);  // row_bcast:15, rows 1,3
  x = dpp_add<0x143, 0xc>(x);  // row_bcast:31, rows 2,3
  return __uint_as_float(__builtin_amdgcn_readlane(__float_as_uint(x), 63));
}

__device__ __forceinline__ float rlane(float x, int l) {
  return __uint_as_float(__builtin_amdgcn_readlane(__float_as_uint(x), l));
}

__device__ __forceinline__ float sigf(float x) {
  return __builtin_amdgcn_rcpf(1.f + __expf(-x));
}
__device__ __forceinline__ float tanhfast(float x) {
  return 1.f - 2.f * __builtin_amdgcn_rcpf(1.f + __expf(2.f * x));
}

__global__ __launch_bounds__(256, 1)
void gru_recurrent_kernel(const float* __restrict__ Whh,
                          const float* __restrict__ bhh,
                          const float* __restrict__ GI,      // [t1-t0][N3]
                          float* __restrict__ out,
                          unsigned long long* hrep,          // [NREG][2][HID]
                          int t0, int t1) {
  __shared__ float lds_h[2][HID];
  const int tid  = threadIdx.x;
  const int lane = tid & 63;
  const int wv   = tid >> 6;
  const int gw   = blockIdx.x * 4 + wv;   // 0..1023
  const int i0   = 2 * gw;
  const int reg  = blockIdx.x & (NREG - 1);

  const int rows[6] = {i0, i0 + 1, HID + i0, HID + i0 + 1, 2 * HID + i0, 2 * HID + i0 + 1};

  // Weights pinned in AGPRs: w[r][jb] covers k = jb*256 + lane*4 + {0..3}
  float4 w[6][8];
#pragma unroll
  for (int r = 0; r < 6; ++r) {
    const float* wr = Whh + (size_t)rows[r] * HID + lane * 4;
#pragma unroll
    for (int jb = 0; jb < 8; ++jb) {
      w[r][jb] = *(const float4*)(wr + jb * 256);
      asm volatile("" : "+a"(w[r][jb].x), "+a"(w[r][jb].y),
                        "+a"(w[r][jb].z), "+a"(w[r][jb].w));
    }
  }

  // wave-uniform biases for the wave's two units
  float br0, br1, bz0, bz1, bn0, bn1;
  {
    float a = 0.f, b = 0.f, c = 0.f;
    if (lane < 2) {
      a = bhh[i0 + lane];
      b = bhh[HID + i0 + lane];
      c = bhh[2 * HID + i0 + lane];
    }
    br0 = rlane(a, 0); br1 = rlane(a, 1);
    bz0 = rlane(b, 0); bz1 = rlane(b, 1);
    bn0 = rlane(c, 0); bn1 = rlane(c, 1);
  }

  // GI prefetch for first step
  float gr = 0.f, gz = 0.f, gn = 0.f;
  if (lane < 2) {
    gr = GI[i0 + lane];
    gz = GI[HID + i0 + lane];
    gn = GI[2 * HID + i0 + lane];
  }

  const int b0 = tid * 4;

  for (int t = t0; t < t1; ++t) {
    // ---- batched-retry poll of this thread's 8 tag-pairs (own region only) ----
    const unsigned long long* hb = hrep + (size_t)reg * 2 * HID + (size_t)(t & 1) * HID;
    const unsigned tag = (unsigned)t;
    unsigned long long p[8];
#pragma unroll
    for (int i = 0; i < 4; ++i) p[i] = ld_pair(hb + b0 + i);
#pragma unroll
    for (int i = 0; i < 4; ++i) p[4 + i] = ld_pair(hb + 1024 + b0 + i);
    for (;;) {
      int stale = 0;
#pragma unroll
      for (int i = 0; i < 8; ++i)
        stale |= ((unsigned)(p[i] >> 32) != tag) ? (1 << i) : 0;
      if (!stale) break;
#pragma unroll
      for (int i = 0; i < 4; ++i)
        if (stale & (1 << i)) p[i] = ld_pair(hb + b0 + i);
#pragma unroll
      for (int i = 0; i < 4; ++i)
        if (stale & (1 << (4 + i))) p[4 + i] = ld_pair(hb + 1024 + b0 + i);
    }

    float* lc = lds_h[t & 1];
    {
      float4 v0, v1;
      v0.x = __uint_as_float((unsigned)p[0]);
      v0.y = __uint_as_float((unsigned)p[1]);
      v0.z = __uint_as_float((unsigned)p[2]);
      v0.w = __uint_as_float((unsigned)p[3]);
      v1.x = __uint_as_float((unsigned)p[4]);
      v1.y = __uint_as_float((unsigned)p[5]);
      v1.z = __uint_as_float((unsigned)p[6]);
      v1.w = __uint_as_float((unsigned)p[7]);
      *(float4*)&lc[b0] = v0;
      *(float4*)&lc[1024 + b0] = v1;
    }

    // prefetch NEXT step's input gates AFTER poll/staging so the poll's
    // vmcnt drain never waits on an HBM load (in-order vmcnt per wave)
    float pr = 0.f, pz = 0.f, pn = 0.f;
    if (t + 1 < t1 && lane < 2) {
      const float* g = GI + (size_t)(t + 1 - t0) * N3;
      pr = g[i0 + lane];
      pz = g[HID + i0 + lane];
      pn = g[2 * HID + i0 + lane];
    }
    __syncthreads();

    // ---- matvec: 6 rows x 2048 (weights in AGPRs) ----
    float acc0 = 0.f, acc1 = 0.f, acc2 = 0.f, acc3 = 0.f, acc4 = 0.f, acc5 = 0.f;
#pragma unroll
    for (int jb = 0; jb < 8; ++jb) {
      float4 hv = *(const float4*)&lc[jb * 256 + lane * 4];
      acc0 = fmaf(w[0][jb].x, hv.x, acc0); acc0 = fmaf(w[0][jb].y, hv.y, acc0);
      acc0 = fmaf(w[0][jb].z, hv.z, acc0); acc0 = fmaf(w[0][jb].w, hv.w, acc0);
      acc1 = fmaf(w[1][jb].x, hv.x, acc1); acc1 = fmaf(w[1][jb].y, hv.y, acc1);
      acc1 = fmaf(w[1][jb].z, hv.z, acc1); acc1 = fmaf(w[1][jb].w, hv.w, acc1);
      acc2 = fmaf(w[2][jb].x, hv.x, acc2); acc2 = fmaf(w[2][jb].y, hv.y, acc2);
      acc2 = fmaf(w[2][jb].z, hv.z, acc2); acc2 = fmaf(w[2][jb].w, hv.w, acc2);
      acc3 = fmaf(w[3][jb].x, hv.x, acc3); acc3 = fmaf(w[3][jb].y, hv.y, acc3);
      acc3 = fmaf(w[3][jb].z, hv.z, acc3); acc3 = fmaf(w[3][jb].w, hv.w, acc3);
      acc4 = fmaf(w[4][jb].x, hv.x, acc4); acc4 = fmaf(w[4][jb].y, hv.y, acc4);
      acc4 = fmaf(w[4][jb].z, hv.z, acc4); acc4 = fmaf(w[4][jb].w, hv.w, acc4);
      acc5 = fmaf(w[5][jb].x, hv.x, acc5); acc5 = fmaf(w[5][jb].y, hv.y, acc5);
      acc5 = fmaf(w[5][jb].z, hv.z, acc5); acc5 = fmaf(w[5][jb].w, hv.w, acc5);
    }

    // ---- DPP reduce -> wave-uniform sums ----
    const float sr0 = wave_sum(acc0), sr1 = wave_sum(acc1);
    const float sz0 = wave_sum(acc2), sz1 = wave_sum(acc3);
    const float sn0 = wave_sum(acc4), sn1 = wave_sum(acc5);

    const float gr0 = rlane(gr, 0), gr1 = rlane(gr, 1);
    const float gz0 = rlane(gz, 0), gz1 = rlane(gz, 1);
    const float gn0 = rlane(gn, 0), gn1 = rlane(gn, 1);

    const float r0 = sigf(gr0 + sr0 + br0);
    const float r1 = sigf(gr1 + sr1 + br1);
    const float z0 = sigf(gz0 + sz0 + bz0);
    const float z1 = sigf(gz1 + sz1 + bz1);
    const float n0 = tanhfast(gn0 + r0 * (sn0 + bn0));
    const float n1 = tanhfast(gn1 + r1 * (sn1 + bn1));
    const float hp0 = lc[i0], hp1 = lc[i0 + 1];
    const float hn0 = (1.f - z0) * n0 + z0 * hp0;
    const float hn1 = (1.f - z1) * n1 + z1 * hp1;

    const float hn = lane ? hn1 : hn0;
    if (lane < 2) {
      // replicated h-propagation stores FIRST (critical path), 8 regions
      unsigned long long pk =
          ((unsigned long long)(unsigned)(t + 1) << 32) | __float_as_uint(hn);
      unsigned long long* hw = hrep + (size_t)((t + 1) & 1) * HID + i0 + lane;
#pragma unroll
      for (int rx = 0; rx < NREG; ++rx)
        __hip_atomic_store(hw + (size_t)rx * 2 * HID, pk,
                           __ATOMIC_RELAXED, __HIP_MEMORY_SCOPE_AGENT);
      if (t == SEQ - 1) {
        out[(size_t)t * HID + i0 + lane] = hn;          // last out row
        out[(size_t)SEQ * HID + i0 + lane] = hn;        // final hidden x2
        out[(size_t)SEQ * HID + HID + i0 + lane] = hn;
      }
    }

    // designated block writes out row t-1 (== staged h_t) coalesced
    if (t > 0 && (t & (NBLK - 1)) == blockIdx.x) {
      float4 v0, v1;
      v0.x = __uint_as_float((unsigned)p[0]);
      v0.y = __uint_as_float((unsigned)p[1]);
      v0.z = __uint_as_float((unsigned)p[2]);
      v0.w = __uint_as_float((unsigned)p[3]);
      v1.x = __uint_as_float((unsigned)p[4]);
      v1.y = __uint_as_float((unsigned)p[5]);
      v1.z = __uint_as_float((unsigned)p[6]);
      v1.w = __uint_as_float((unsigned)p[7]);
      float* orow = out + (size_t)(t - 1) * HID;
      *(float4*)(orow + b0) = v0;
      *(float4*)(orow + 1024 + b0) = v1;
    }

    gr = pr; gz = pz; gn = pn;
  }
}

// ---------------------------------------------------------------------------
extern "C" void kernel_launch(void* const* d_in, const int* in_sizes, int n_in,
                              void* d_out, int out_size, void* d_ws, size_t ws_size,
                              hipStream_t stream) {
  const float* x    = (const float*)d_in[0];
  const float* w_ih = (const float*)d_in[1];
  const float* w_hh = (const float*)d_in[2];
  const float* b_ih = (const float*)d_in[3];
  const float* b_hh = (const float*)d_in[4];
  float* out = (float*)d_out;

  const size_t hrep_bytes = (size_t)NREG * 2 * HID * 8;

  int chunk = SEQ;
  while (chunk > 128 &&
         (size_t)chunk * N3 * 4 + hrep_bytes + 256 > ws_size)
    chunk >>= 1;

  const size_t gi_bytes = (size_t)chunk * N3 * 4;
  float* gi = (float*)d_ws;
  unsigned long long* hrep = (unsigned long long*)((char*)d_ws + gi_bytes);

  // h_0 = 0.0f tagged epoch 0 == all-zero bytes; clears all regions
  (void)hipMemsetAsync(hrep, 0, hrep_bytes, stream);

  for (int t0 = 0; t0 < SEQ; t0 += chunk) {
    dim3 ggrid(N3 / BN, chunk / BM);
    gi_gemm_kernel<<<ggrid, 256, 0, stream>>>(x + (size_t)t0 * HID, w_ih, b_ih, gi);
    gru_recurrent_kernel<<<NBLK, 256, 0, stream>>>(w_hh, b_hh, gi, out, hrep,
                                                   t0, t0 + chunk);
  }
}